// Round 5
// baseline (565.709 us; speedup 1.0000x reference)
//
#include <hip/hip_runtime.h>
#include <cstdint>
#include <cstddef>

#define B_    16
#define C_    256
#define HW_   64
#define N_    4096      // 64*64 spatial
#define K_    512
#define NROW_ 65536     // B_*N_

typedef __attribute__((ext_vector_type(8))) __bf16 bf16x8;
typedef __attribute__((ext_vector_type(4))) float floatx4;

struct P2 { float v1; int k1; float v2; int k2; };

__device__ __forceinline__ bool lexless(float v, int k, float bv, int bk) {
    return (v < bv) || (v == bv && k < bk);
}
__device__ __forceinline__ void ins2(float v, int k, float& v1, int& k1, float& v2, int& k2) {
    if (lexless(v, k, v1, k1)) { v2 = v1; k2 = k1; v1 = v; k1 = k; }
    else if (lexless(v, k, v2, k2)) { v2 = v; k2 = k; }
}

// Bpack layout: [chunk 2][ct 8][plane 2][n 256][c' 32] bf16 (512 KB total).
// Each (chunk,ct,plane) tile is a dense 16 KB block; staging in main is
// chunk-linear: chunk_id cid = q*256+tid maps to (n,qq)=(cid>>2,cid&3),
// source elems cid*8..cid*8+7 — i.e. plain linear copy, fully coalesced.

// ---------------- kernel 1: codebook prep: e2 + packed bf16 hi/lo tiles -------
__global__ void prep_kernel(const float* __restrict__ cb, float* __restrict__ e2,
                            __bf16* __restrict__ Bpack, double* __restrict__ lossAcc) {
    int k = blockIdx.x, t = threadIdx.x;
    if (k == 0 && t == 0) *lossAcc = 0.0;
    int chunk = k >> 8, n = k & 255;
    float4 v = *(const float4*)(cb + (size_t)k * C_ + t * 4);
    float vv[4] = {v.x, v.y, v.z, v.w};
    __bf16 h[4], l[4];
    float s = 0.f;
    #pragma unroll
    for (int i = 0; i < 4; ++i) {
        h[i] = (__bf16)vv[i];
        l[i] = (__bf16)(vv[i] - (float)h[i]);
        s = fmaf(vv[i], vv[i], s);
    }
    int ct = t >> 3, cp = (t * 4) & 31;
    size_t tb = ((size_t)((chunk * 8 + ct) * 2)) * 8192 + n * 32 + cp;
    *(ushort4*)&Bpack[tb]        = *(ushort4*)h;   // hi plane
    *(ushort4*)&Bpack[tb + 8192] = *(ushort4*)l;   // lo plane
    #pragma unroll
    for (int off = 32; off; off >>= 1) s += __shfl_down(s, off);
    if (t == 0) e2[k] = s;
}

// ---------------- kernel 2: pipelined split-bf16 MFMA GEMM + top-2 ------------
// grid (Mtile=1024, chunk=2); block 256 (4 waves). Tile 64 rows x 256 codes.
// Software pipeline: A(ct+1)/B(ct+1) global->regs issued BEFORE the MFMA of ct,
// first use after the next barrier -> HBM latency hides under MFMA+LDS.
__launch_bounds__(256, 3)
__global__ void main_kernel(const float* __restrict__ pq,
                            const __bf16* __restrict__ Bpack,
                            const float* __restrict__ e2, P2* __restrict__ partials,
                            float* __restrict__ x2) {
    const int Mtile = blockIdx.x, chunk = blockIdx.y;
    const int tid = threadIdx.x;
    const int wave = tid >> 6, lane = tid & 63;
    const int lm = lane & 15, quad = lane >> 4;
    const int b = Mtile >> 6;
    const int s0 = (Mtile * 64) & 4095;
    const int n0 = chunk * 256;

    __shared__ __bf16 As[2][64][40];    // hi/lo, 80-B rows (2-way bank max: free)
    __shared__ __bf16 Bs[2][256][40];
    __shared__ float  xs[4][64];

    floatx4 acc[4][4];
    #pragma unroll
    for (int i = 0; i < 4; ++i)
        #pragma unroll
        for (int j = 0; j < 4; ++j) acc[i][j] = (floatx4)0.f;

    const int sm = lane, cg = wave;
    const float* pqA = pq + (size_t)b * (C_ * N_) + s0 + sm;
    const __bf16* bpk = Bpack + (size_t)chunk * 131072;
    const int bn = tid >> 2, bq = tid & 3;     // B LDS dest: row q*64+bn, chunk bq

    float a_regs[8];
    uint4 bh[4], bl[4];
    // prologue: ct=0 loads
    #pragma unroll
    for (int i = 0; i < 8; ++i) a_regs[i] = pqA[(size_t)(cg * 8 + i) * N_];
    #pragma unroll
    for (int q = 0; q < 4; ++q) {
        bh[q] = *(const uint4*)(bpk + (q * 256 + tid) * 8);
        bl[q] = *(const uint4*)(bpk + 8192 + (q * 256 + tid) * 8);
    }
    float x2loc = 0.f;

    for (int ct = 0; ct < 8; ++ct) {
        // convert A regs (vmcnt wait lands here — covered by previous MFMA)
        bf16x8 hi, lo;
        #pragma unroll
        for (int i = 0; i < 8; ++i) {
            hi[i] = (__bf16)a_regs[i];
            lo[i] = (__bf16)(a_regs[i] - (float)hi[i]);
            x2loc = fmaf(a_regs[i], a_regs[i], x2loc);
        }
        __syncthreads();                       // prior MFMA ds_reads done
        *(bf16x8*)&As[0][sm][cg * 8] = hi;
        *(bf16x8*)&As[1][sm][cg * 8] = lo;
        #pragma unroll
        for (int q = 0; q < 4; ++q) {
            *(uint4*)&Bs[0][q * 64 + bn][bq * 8] = bh[q];
            *(uint4*)&Bs[1][q * 64 + bn][bq * 8] = bl[q];
        }
        __syncthreads();                       // tiles visible

        // prefetch ct+1 (in flight across the MFMA section)
        if (ct < 7) {
            const __bf16* tbp = bpk + (ct + 1) * 16384;
            #pragma unroll
            for (int i = 0; i < 8; ++i)
                a_regs[i] = pqA[(size_t)((ct + 1) * 32 + cg * 8 + i) * N_];
            #pragma unroll
            for (int q = 0; q < 4; ++q) {
                bh[q] = *(const uint4*)(tbp + (q * 256 + tid) * 8);
                bl[q] = *(const uint4*)(tbp + 8192 + (q * 256 + tid) * 8);
            }
        }

        // MFMA: (x1,e1), (x1,e2), (x2,e1) with frag reuse
        const int lk = quad * 8;
        bf16x8 a1[4], b1v[4];
        #pragma unroll
        for (int mt = 0; mt < 4; ++mt) a1[mt] = *(const bf16x8*)&As[0][mt * 16 + lm][lk];
        #pragma unroll
        for (int nt = 0; nt < 4; ++nt) b1v[nt] = *(const bf16x8*)&Bs[0][wave * 64 + nt * 16 + lm][lk];
        #pragma unroll
        for (int mt = 0; mt < 4; ++mt)
            #pragma unroll
            for (int nt = 0; nt < 4; ++nt)
                acc[mt][nt] = __builtin_amdgcn_mfma_f32_16x16x32_bf16(a1[mt], b1v[nt], acc[mt][nt], 0, 0, 0);
        bf16x8 b2v[4];
        #pragma unroll
        for (int nt = 0; nt < 4; ++nt) b2v[nt] = *(const bf16x8*)&Bs[1][wave * 64 + nt * 16 + lm][lk];
        #pragma unroll
        for (int mt = 0; mt < 4; ++mt)
            #pragma unroll
            for (int nt = 0; nt < 4; ++nt)
                acc[mt][nt] = __builtin_amdgcn_mfma_f32_16x16x32_bf16(a1[mt], b2v[nt], acc[mt][nt], 0, 0, 0);
        bf16x8 a2[4];
        #pragma unroll
        for (int mt = 0; mt < 4; ++mt) a2[mt] = *(const bf16x8*)&As[1][mt * 16 + lm][lk];
        #pragma unroll
        for (int mt = 0; mt < 4; ++mt)
            #pragma unroll
            for (int nt = 0; nt < 4; ++nt)
                acc[mt][nt] = __builtin_amdgcn_mfma_f32_16x16x32_bf16(a2[mt], b1v[nt], acc[mt][nt], 0, 0, 0);
    }

    __syncthreads();          // drain K-loop LDS reads (As reused below)
    xs[cg][sm] = x2loc;

    // ---- epilogue: per-wave top-2 over its 64 codes -> LDS cross-wave merge ----
    P2* mergebuf = (P2*)&As[0][0][0];   // 4 KB, overlays dead As

    const int kbase = n0 + wave * 64;
    float e2v[4];
    #pragma unroll
    for (int nt = 0; nt < 4; ++nt) e2v[nt] = e2[kbase + nt * 16 + lm];

    #pragma unroll
    for (int mt = 0; mt < 4; ++mt) {
        #pragma unroll
        for (int r = 0; r < 4; ++r) {
            float v1 = __builtin_inff(), v2 = __builtin_inff();
            int k1 = 0x7fffffff, k2 = 0x7fffffff;
            #pragma unroll
            for (int nt = 0; nt < 4; ++nt) {
                float v = fmaf(-2.f, acc[mt][nt][r], e2v[nt]);
                ins2(v, kbase + nt * 16 + lm, v1, k1, v2, k2);
            }
            #pragma unroll
            for (int m = 1; m < 16; m <<= 1) {
                float ov1 = __shfl_xor(v1, m); int ok1 = __shfl_xor(k1, m);
                float ov2 = __shfl_xor(v2, m); int ok2 = __shfl_xor(k2, m);
                ins2(ov1, ok1, v1, k1, v2, k2);
                ins2(ov2, ok2, v1, k1, v2, k2);
            }
            if (lm == 0) {
                P2 p; p.v1 = v1; p.k1 = k1; p.v2 = v2; p.k2 = k2;
                mergebuf[wave * 64 + mt * 16 + quad * 4 + r] = p;
            }
        }
    }
    __syncthreads();

    if (tid < 64) {
        float v1 = __builtin_inff(), v2 = __builtin_inff();
        int k1 = 0x7fffffff, k2 = 0x7fffffff;
        #pragma unroll
        for (int w = 0; w < 4; ++w) {
            P2 p = mergebuf[w * 64 + tid];
            ins2(p.v1, p.k1, v1, k1, v2, k2);
            ins2(p.v2, p.k2, v1, k1, v2, k2);
        }
        P2 p; p.v1 = v1; p.k1 = k1; p.v2 = v2; p.k2 = k2;
        partials[(size_t)chunk * NROW_ + Mtile * 64 + tid] = p;
        if (chunk == 0)
            x2[Mtile * 64 + tid] = xs[0][tid] + xs[1][tid] + xs[2][tid] + xs[3][tid];
    }
}

// ---------------- kernel 3: fused merge + refine + loss + gather --------------
// Output flat position p uses the winner of query row sigma(p) (H/W swap).
#define MARGIN 0.05f
__global__ void scatter_merge_kernel(const P2* __restrict__ partials,
                                     const float* __restrict__ x2arr,
                                     const float* __restrict__ pq,
                                     const float* __restrict__ cb,
                                     double* __restrict__ lossAcc,
                                     float* __restrict__ out) {
    int ntile = blockIdx.x, b = blockIdx.y, tid = threadIdx.x;
    int wave = tid >> 6;
    __shared__ int idxs[64];
    __shared__ double lred[4];
    __shared__ float tile[64][65];

    double myloss = 0.0;
    if (tid < 64) {
        int p = ntile * 64 + tid;                       // output flat spatial pos
        int s = ((p & 63) << 6) | (p >> 6);             // sigma (involution)
        int row = (b << 12) | s;
        float v1 = __builtin_inff(), v2 = __builtin_inff();
        int k1 = 0x7fffffff, k2 = 0x7fffffff;
        #pragma unroll
        for (int c = 0; c < 2; ++c) {
            P2 pp = partials[(size_t)c * NROW_ + row];
            ins2(pp.v1, pp.k1, v1, k1, v2, k2);
            ins2(pp.v2, pp.k2, v1, k1, v2, k2);
        }
        int kwin = k1;
        double d2min;
        if (v2 - v1 < MARGIN) {
            const float* xp  = pq + (size_t)b * (C_ * N_) + s;
            const float* ca  = cb + (size_t)k1 * C_;
            const float* cbp = cb + (size_t)k2 * C_;
            double da = 0.0, db = 0.0;
            for (int c = 0; c < C_; ++c) {
                double xv = (double)xp[(size_t)c * N_];
                double ea = xv - (double)ca[c];  da += ea * ea;
                double eb = xv - (double)cbp[c]; db += eb * eb;
            }
            if (db < da || (db == da && k2 < k1)) { kwin = k2; d2min = db; }
            else d2min = da;
        } else {
            d2min = (double)(x2arr[row] + v1);
        }
        idxs[tid] = kwin;
        myloss = d2min;
    }
    double sd = myloss;
    #pragma unroll
    for (int off = 32; off; off >>= 1) sd += __shfl_down(sd, off);
    if ((tid & 63) == 0) lred[wave] = sd;
    __syncthreads();
    if (tid == 0) atomicAdd(lossAcc, lred[0] + lred[1] + lred[2] + lred[3]);

    for (int cc = 0; cc < 4; ++cc) {
        int c0 = cc * 64;
        #pragma unroll
        for (int pp = 0; pp < 16; ++pp) {
            int i = pp * 4 + (tid >> 6);
            int c = tid & 63;
            tile[i][c] = cb[(size_t)idxs[i] * C_ + c0 + c];   // coalesced rows
        }
        __syncthreads();
        #pragma unroll
        for (int pp = 0; pp < 16; ++pp) {
            int cl = pp * 4 + (tid >> 6);
            int nl = tid & 63;
            out[((size_t)(b * C_ + c0 + cl)) * N_ + ntile * 64 + nl] = tile[nl][cl];
        }
        __syncthreads();
    }
}

// ---------------- kernel 4: loss finalize ------------------------------------
__global__ void finalize_kernel(const double* __restrict__ lossAcc, float* __restrict__ out) {
    out[(size_t)B_ * C_ * N_] =
        (float)(1.25 * (*lossAcc) / (double)((size_t)B_ * N_ * C_));
}

// ---------------- launch ------------------------------------------------------
extern "C" void kernel_launch(void* const* d_in, const int* in_sizes, int n_in,
                              void* d_out, int out_size, void* d_ws, size_t ws_size,
                              hipStream_t stream) {
    const float* pq = (const float*)d_in[0];   // [16,256,64,64]
    const float* cb = (const float*)d_in[1];   // [512,256]
    float* out = (float*)d_out;                // 4194304 out + 1 loss
    char* ws = (char*)d_ws;
    double* lossAcc = (double*)ws;                            // 16 B
    float*  e2    = (float*)(ws + 16);                        // 2 KB
    float*  x2    = (float*)(ws + 16 + 2048);                 // 256 KB
    __bf16* Bpack = (__bf16*)(ws + 16 + 2048 + 262144);       // 512 KB
    P2* partials  = (P2*)(ws + 16 + 2048 + 262144 + 524288);  // 2 MB

    prep_kernel<<<K_, 64, 0, stream>>>(cb, e2, Bpack, lossAcc);
    main_kernel<<<dim3(1024, 2), 256, 0, stream>>>(pq, Bpack, e2, partials, x2);
    scatter_merge_kernel<<<dim3(HW_, B_), 256, 0, stream>>>(partials, x2, pq, cb, lossAcc, out);
    finalize_kernel<<<1, 1, 0, stream>>>(lossAcc, out);
}

// Round 6
// 436.525 us; speedup vs baseline: 1.2959x; 1.2959x over previous
//
#include <hip/hip_runtime.h>
#include <cstdint>
#include <cstddef>

#define B_    16
#define C_    256
#define HW_   64
#define N_    4096      // 64*64 spatial
#define K_    512
#define NROW_ 65536     // B_*N_

typedef __attribute__((ext_vector_type(8))) __bf16 bf16x8;
typedef __attribute__((ext_vector_type(4))) float floatx4;
typedef __attribute__((address_space(3))) __bf16 lds_bf16;
typedef __attribute__((address_space(1))) const __bf16 glob_bf16;

struct P2 { float v1; int k1; float v2; int k2; };

__device__ __forceinline__ bool lexless(float v, int k, float bv, int bk) {
    return (v < bv) || (v == bv && k < bk);
}
__device__ __forceinline__ void ins2(float v, int k, float& v1, int& k1, float& v2, int& k2) {
    if (lexless(v, k, v1, k1)) { v2 = v1; k2 = k1; v1 = v; k1 = k; }
    else if (lexless(v, k, v2, k2)) { v2 = v; k2 = k; }
}

// Bpack layout: [chunk 2][ct 8][plane 2][cq 4][n 256][i 8] bf16, 512 KB.
// Per (chunk,ct): one dense 32 KB block, byte-identical to the Bs LDS tile, so
// global_load_lds (uniform LDS base + lane*16) stages it with a linear copy.

// ---------------- kernel 1: codebook prep: e2 + packed bf16 hi/lo tiles -------
__global__ void prep_kernel(const float* __restrict__ cb, float* __restrict__ e2,
                            __bf16* __restrict__ Bpack, double* __restrict__ lossAcc) {
    int k = blockIdx.x, t = threadIdx.x;
    if (k == 0 && t == 0) *lossAcc = 0.0;
    int chunk = k >> 8, n = k & 255;
    float4 v = *(const float4*)(cb + (size_t)k * C_ + t * 4);
    float vv[4] = {v.x, v.y, v.z, v.w};
    __bf16 h[4], l[4];
    float s = 0.f;
    #pragma unroll
    for (int i = 0; i < 4; ++i) {
        h[i] = (__bf16)vv[i];
        l[i] = (__bf16)(vv[i] - (float)h[i]);
        s = fmaf(vv[i], vv[i], s);
    }
    // c = t*4 + j:  ct = c>>5, cq = (c>>3)&3, i = c&7 (i0 = (t&1)*4, 4 consec)
    int ct = t >> 3, cq = (t >> 1) & 3, i0 = (t & 1) * 4;
    size_t base = (size_t)(chunk * 8 + ct) * 16384;          // per-(chunk,ct) tile
    size_t off0 = base + ((size_t)(0 * 4 + cq) * 256 + n) * 8 + i0;   // hi plane
    size_t off1 = base + ((size_t)(1 * 4 + cq) * 256 + n) * 8 + i0;   // lo plane
    *(ushort4*)&Bpack[off0] = *(ushort4*)h;
    *(ushort4*)&Bpack[off1] = *(ushort4*)l;
    #pragma unroll
    for (int off = 32; off; off >>= 1) s += __shfl_down(s, off);
    if (t == 0) e2[k] = s;
}

// ---------------- kernel 2: split-bf16 MFMA GEMM + per-row top-2 --------------
// grid (Mtile=1024, chunk=2); block 256 (4 waves). Tile 64 rows x 256 codes.
// B staged via global_load_lds DMA (no VGPRs); A staged via 8 coalesced loads +
// in-register bf16 hi/lo split. m97-style 2-barrier K-loop.
__launch_bounds__(256, 2)
__global__ void main_kernel(const float* __restrict__ pq,
                            const __bf16* __restrict__ Bpack,
                            const float* __restrict__ e2, P2* __restrict__ partials,
                            float* __restrict__ x2) {
    const int Mtile = blockIdx.x, chunk = blockIdx.y;
    const int tid = threadIdx.x;
    const int wave = tid >> 6, lane = tid & 63;
    const int lm = lane & 15, quad = lane >> 4;
    const int b = Mtile >> 6;
    const int s0 = (Mtile * 64) & 4095;
    const int n0 = chunk * 256;

    __shared__ __bf16 As[2][64][40];   // [plane][m][c'] pad-40 (2-way max: free)
    __shared__ __bf16 Bs[16384];       // [plane 2][cq 4][n 256][i 8] dense 32 KB
    __shared__ float  xs[4][64];

    floatx4 acc[4][4];
    #pragma unroll
    for (int i = 0; i < 4; ++i)
        #pragma unroll
        for (int j = 0; j < 4; ++j) acc[i][j] = (floatx4)0.f;

    const int sm = lane, cg = wave;                 // A: row sm, c-group cg
    const float* pqA = pq + (size_t)b * (C_ * N_) + s0 + sm;
    const __bf16* bpk = Bpack + (size_t)chunk * 131072;

    float x2loc = 0.f;

    for (int ct = 0; ct < 8; ++ct) {
        const int c0 = ct * 32;
        __syncthreads();                            // prev compute done; LDS free

        // ---- B: 8 fire-and-forget DMA instrs (1 KB/wave each, linear) ----
        const __bf16* btile = bpk + ct * 16384;
        #pragma unroll
        for (int j = 0; j < 8; ++j) {
            int Lw = wave * 8 + j;                  // wave-uniform slot
            __builtin_amdgcn_global_load_lds(
                (const glob_bf16*)(btile + (size_t)(Lw * 64 + lane) * 8),
                (lds_bf16*)&Bs[Lw * 512], 16, 0, 0);
        }

        // ---- A: 8 coalesced fp32 loads, split to bf16 hi/lo ----
        float av[8];
        #pragma unroll
        for (int i = 0; i < 8; ++i)
            av[i] = pqA[(size_t)(c0 + cg * 8 + i) * N_];
        bf16x8 hi, lo;
        #pragma unroll
        for (int i = 0; i < 8; ++i) {
            hi[i] = (__bf16)av[i];
            lo[i] = (__bf16)(av[i] - (float)hi[i]);
            x2loc = fmaf(av[i], av[i], x2loc);
        }
        *(bf16x8*)&As[0][sm][cg * 8] = hi;
        *(bf16x8*)&As[1][sm][cg * 8] = lo;

        __syncthreads();                            // vmcnt+lgkm drained: tiles live

        // ---- MFMA: (x1,e1), (x1,e2), (x2,e1) with frag reuse ----
        const int lk = quad * 8;
        bf16x8 a1[4], b1v[4];
        #pragma unroll
        for (int mt = 0; mt < 4; ++mt) a1[mt] = *(const bf16x8*)&As[0][mt * 16 + lm][lk];
        #pragma unroll
        for (int nt = 0; nt < 4; ++nt)
            b1v[nt] = *(const bf16x8*)&Bs[((0 * 4 + quad) * 256 + wave * 64 + nt * 16 + lm) * 8];
        #pragma unroll
        for (int mt = 0; mt < 4; ++mt)
            #pragma unroll
            for (int nt = 0; nt < 4; ++nt)
                acc[mt][nt] = __builtin_amdgcn_mfma_f32_16x16x32_bf16(a1[mt], b1v[nt], acc[mt][nt], 0, 0, 0);
        bf16x8 b2v[4];
        #pragma unroll
        for (int nt = 0; nt < 4; ++nt)
            b2v[nt] = *(const bf16x8*)&Bs[((1 * 4 + quad) * 256 + wave * 64 + nt * 16 + lm) * 8];
        #pragma unroll
        for (int mt = 0; mt < 4; ++mt)
            #pragma unroll
            for (int nt = 0; nt < 4; ++nt)
                acc[mt][nt] = __builtin_amdgcn_mfma_f32_16x16x32_bf16(a1[mt], b2v[nt], acc[mt][nt], 0, 0, 0);
        bf16x8 a2[4];
        #pragma unroll
        for (int mt = 0; mt < 4; ++mt) a2[mt] = *(const bf16x8*)&As[1][mt * 16 + lm][lk];
        #pragma unroll
        for (int mt = 0; mt < 4; ++mt)
            #pragma unroll
            for (int nt = 0; nt < 4; ++nt)
                acc[mt][nt] = __builtin_amdgcn_mfma_f32_16x16x32_bf16(a2[mt], b1v[nt], acc[mt][nt], 0, 0, 0);
    }

    __syncthreads();          // drain K-loop LDS reads (As reused below)
    xs[cg][sm] = x2loc;

    // ---- epilogue: per-wave top-2 over its 64 codes -> LDS cross-wave merge ----
    P2* mergebuf = (P2*)&As[0][0][0];   // 4 KB, overlays dead As

    const int kbase = n0 + wave * 64;
    float e2v[4];
    #pragma unroll
    for (int nt = 0; nt < 4; ++nt) e2v[nt] = e2[kbase + nt * 16 + lm];

    #pragma unroll
    for (int mt = 0; mt < 4; ++mt) {
        #pragma unroll
        for (int r = 0; r < 4; ++r) {
            float v1 = __builtin_inff(), v2 = __builtin_inff();
            int k1 = 0x7fffffff, k2 = 0x7fffffff;
            #pragma unroll
            for (int nt = 0; nt < 4; ++nt) {
                float v = fmaf(-2.f, acc[mt][nt][r], e2v[nt]);
                ins2(v, kbase + nt * 16 + lm, v1, k1, v2, k2);
            }
            #pragma unroll
            for (int m = 1; m < 16; m <<= 1) {
                float ov1 = __shfl_xor(v1, m); int ok1 = __shfl_xor(k1, m);
                float ov2 = __shfl_xor(v2, m); int ok2 = __shfl_xor(k2, m);
                ins2(ov1, ok1, v1, k1, v2, k2);
                ins2(ov2, ok2, v1, k1, v2, k2);
            }
            if (lm == 0) {
                P2 p; p.v1 = v1; p.k1 = k1; p.v2 = v2; p.k2 = k2;
                mergebuf[wave * 64 + mt * 16 + quad * 4 + r] = p;
            }
        }
    }
    __syncthreads();

    if (tid < 64) {
        float v1 = __builtin_inff(), v2 = __builtin_inff();
        int k1 = 0x7fffffff, k2 = 0x7fffffff;
        #pragma unroll
        for (int w = 0; w < 4; ++w) {
            P2 p = mergebuf[w * 64 + tid];
            ins2(p.v1, p.k1, v1, k1, v2, k2);
            ins2(p.v2, p.k2, v1, k1, v2, k2);
        }
        P2 p; p.v1 = v1; p.k1 = k1; p.v2 = v2; p.k2 = k2;
        partials[(size_t)chunk * NROW_ + Mtile * 64 + tid] = p;
        if (chunk == 0)
            x2[Mtile * 64 + tid] = xs[0][tid] + xs[1][tid] + xs[2][tid] + xs[3][tid];
    }
}

// ---------------- kernel 3: fused merge + refine + loss + gather --------------
// Output flat position p uses the winner of query row sigma(p) (H/W swap).
#define MARGIN 0.05f
__global__ void scatter_merge_kernel(const P2* __restrict__ partials,
                                     const float* __restrict__ x2arr,
                                     const float* __restrict__ pq,
                                     const float* __restrict__ cb,
                                     double* __restrict__ lossAcc,
                                     float* __restrict__ out) {
    int ntile = blockIdx.x, b = blockIdx.y, tid = threadIdx.x;
    int wave = tid >> 6;
    __shared__ int idxs[64];
    __shared__ double lred[4];
    __shared__ float tile[64][65];

    double myloss = 0.0;
    if (tid < 64) {
        int p = ntile * 64 + tid;                       // output flat spatial pos
        int s = ((p & 63) << 6) | (p >> 6);             // sigma (involution)
        int row = (b << 12) | s;
        float v1 = __builtin_inff(), v2 = __builtin_inff();
        int k1 = 0x7fffffff, k2 = 0x7fffffff;
        #pragma unroll
        for (int c = 0; c < 2; ++c) {
            P2 pp = partials[(size_t)c * NROW_ + row];
            ins2(pp.v1, pp.k1, v1, k1, v2, k2);
            ins2(pp.v2, pp.k2, v1, k1, v2, k2);
        }
        int kwin = k1;
        double d2min;
        if (v2 - v1 < MARGIN) {
            const float* xp  = pq + (size_t)b * (C_ * N_) + s;
            const float* ca  = cb + (size_t)k1 * C_;
            const float* cbp = cb + (size_t)k2 * C_;
            double da = 0.0, db = 0.0;
            for (int c = 0; c < C_; ++c) {
                double xv = (double)xp[(size_t)c * N_];
                double ea = xv - (double)ca[c];  da += ea * ea;
                double eb = xv - (double)cbp[c]; db += eb * eb;
            }
            if (db < da || (db == da && k2 < k1)) { kwin = k2; d2min = db; }
            else d2min = da;
        } else {
            d2min = (double)(x2arr[row] + v1);
        }
        idxs[tid] = kwin;
        myloss = d2min;
    }
    double sd = myloss;
    #pragma unroll
    for (int off = 32; off; off >>= 1) sd += __shfl_down(sd, off);
    if ((tid & 63) == 0) lred[wave] = sd;
    __syncthreads();
    if (tid == 0) atomicAdd(lossAcc, lred[0] + lred[1] + lred[2] + lred[3]);

    for (int cc = 0; cc < 4; ++cc) {
        int c0 = cc * 64;
        #pragma unroll
        for (int pp = 0; pp < 16; ++pp) {
            int i = pp * 4 + (tid >> 6);
            int c = tid & 63;
            tile[i][c] = cb[(size_t)idxs[i] * C_ + c0 + c];   // coalesced rows
        }
        __syncthreads();
        #pragma unroll
        for (int pp = 0; pp < 16; ++pp) {
            int cl = pp * 4 + (tid >> 6);
            int nl = tid & 63;
            out[((size_t)(b * C_ + c0 + cl)) * N_ + ntile * 64 + nl] = tile[nl][cl];
        }
        __syncthreads();
    }
}

// ---------------- kernel 4: loss finalize ------------------------------------
__global__ void finalize_kernel(const double* __restrict__ lossAcc, float* __restrict__ out) {
    out[(size_t)B_ * C_ * N_] =
        (float)(1.25 * (*lossAcc) / (double)((size_t)B_ * N_ * C_));
}

// ---------------- launch ------------------------------------------------------
extern "C" void kernel_launch(void* const* d_in, const int* in_sizes, int n_in,
                              void* d_out, int out_size, void* d_ws, size_t ws_size,
                              hipStream_t stream) {
    const float* pq = (const float*)d_in[0];   // [16,256,64,64]
    const float* cb = (const float*)d_in[1];   // [512,256]
    float* out = (float*)d_out;                // 4194304 out + 1 loss
    char* ws = (char*)d_ws;
    double* lossAcc = (double*)ws;                            // 16 B
    float*  e2    = (float*)(ws + 16);                        // 2 KB
    float*  x2    = (float*)(ws + 16 + 2048);                 // 256 KB
    __bf16* Bpack = (__bf16*)(ws + 16 + 2048 + 262144);       // 512 KB
    P2* partials  = (P2*)(ws + 16 + 2048 + 262144 + 524288);  // 2 MB

    prep_kernel<<<K_, 64, 0, stream>>>(cb, e2, Bpack, lossAcc);
    main_kernel<<<dim3(1024, 2), 256, 0, stream>>>(pq, Bpack, e2, partials, x2);
    scatter_merge_kernel<<<dim3(HW_, B_), 256, 0, stream>>>(partials, x2, pq, cb, lossAcc, out);
    finalize_kernel<<<1, 1, 0, stream>>>(lossAcc, out);
}

// Round 7
// 370.928 us; speedup vs baseline: 1.5251x; 1.1768x over previous
//
#include <hip/hip_runtime.h>
#include <cstdint>
#include <cstddef>

#define B_    16
#define C_    256
#define HW_   64
#define N_    4096      // 64*64 spatial
#define K_    512
#define NROW_ 65536     // B_*N_

typedef __attribute__((ext_vector_type(8))) __bf16 bf16x8;
typedef __attribute__((ext_vector_type(4))) float floatx4;
typedef __attribute__((address_space(3))) __bf16 lds_bf16;
typedef __attribute__((address_space(1))) const __bf16 glob_bf16;

struct P2 { float v1; int k1; float v2; int k2; };

__device__ __forceinline__ bool lexless(float v, int k, float bv, int bk) {
    return (v < bv) || (v == bv && k < bk);
}
__device__ __forceinline__ void ins2(float v, int k, float& v1, int& k1, float& v2, int& k2) {
    if (lexless(v, k, v1, k1)) { v2 = v1; k2 = k1; v1 = v; k1 = k; }
    else if (lexless(v, k, v2, k2)) { v2 = v; k2 = k; }
}

// Bpack layout: [ct 8][plane 2][cq 4][n 512][i 8] bf16, 512 KB.
// Per ct: one dense 64 KB block, byte-identical to the Bs LDS tile, so
// global_load_lds (uniform LDS base + lane*16) stages it with a linear copy.

// ---------------- kernel 1: codebook prep: e2 + packed bf16 hi/lo tiles -------
__global__ void prep_kernel(const float* __restrict__ cb, float* __restrict__ e2,
                            __bf16* __restrict__ Bpack, double* __restrict__ lossAcc) {
    int n = blockIdx.x, t = threadIdx.x;
    if (n == 0 && t == 0) *lossAcc = 0.0;
    float4 v = *(const float4*)(cb + (size_t)n * C_ + t * 4);
    float vv[4] = {v.x, v.y, v.z, v.w};
    __bf16 h[4], l[4];
    float s = 0.f;
    #pragma unroll
    for (int i = 0; i < 4; ++i) {
        h[i] = (__bf16)vv[i];
        l[i] = (__bf16)(vv[i] - (float)h[i]);
        s = fmaf(vv[i], vv[i], s);
    }
    // c = t*4 + j:  ct = t>>3, cq = (t>>1)&3, i0 = (t&1)*4
    int ct = t >> 3, cq = (t >> 1) & 3, i0 = (t & 1) * 4;
    size_t base = (size_t)ct * 32768;
    size_t off0 = base + ((size_t)(0 * 4 + cq) * 512 + n) * 8 + i0;   // hi plane
    size_t off1 = base + ((size_t)(1 * 4 + cq) * 512 + n) * 8 + i0;   // lo plane
    *(ushort4*)&Bpack[off0] = *(ushort4*)h;
    *(ushort4*)&Bpack[off1] = *(ushort4*)l;
    #pragma unroll
    for (int off = 32; off; off >>= 1) s += __shfl_down(s, off);
    if (t == 0) e2[n] = s;
}

// ---------------- kernel 2: split-bf16 MFMA GEMM + per-row top-2 over 512 -----
// grid 1024; block 256 (4 waves). Tile: 64 rows x ALL 512 codes (wave owns 128).
// A: register-prefetched (ct+1 issued after barrier-2, vmcnt lands next iter).
// B: global_load_lds DMA from L2-resident Bpack (no VGPR results).
__launch_bounds__(256, 2)
__global__ void main_kernel(const float* __restrict__ pq,
                            const __bf16* __restrict__ Bpack,
                            const float* __restrict__ e2, P2* __restrict__ partials,
                            float* __restrict__ x2) {
    const int Mtile = blockIdx.x;
    const int tid = threadIdx.x;
    const int wave = tid >> 6, lane = tid & 63;
    const int lm = lane & 15, quad = lane >> 4;
    const int b = Mtile >> 6;
    const int s0 = (Mtile * 64) & 4095;

    __shared__ __bf16 As[2][64][40];   // [plane][m][c'] pad-40 (2-way bank max: free)
    __shared__ __bf16 Bs[32768];       // [plane 2][cq 4][n 512][i 8] dense 64 KB
    __shared__ float  xs[4][64];

    floatx4 acc[4][8];                 // [mt][nt] -> 128 VGPRs
    #pragma unroll
    for (int i = 0; i < 4; ++i)
        #pragma unroll
        for (int j = 0; j < 8; ++j) acc[i][j] = (floatx4)0.f;

    const float* pqA = pq + (size_t)b * (C_ * N_) + s0 + lane;

    float a_regs[8];
    #pragma unroll
    for (int i = 0; i < 8; ++i) a_regs[i] = pqA[(size_t)(wave * 8 + i) * N_];
    float x2loc = 0.f;

    for (int ct = 0; ct < 8; ++ct) {
        // ---- convert prefetched A (vmcnt wait lands here, covered by prev MFMA) ----
        bf16x8 hi, lo;
        #pragma unroll
        for (int i = 0; i < 8; ++i) {
            float a = a_regs[i];
            hi[i] = (__bf16)a;
            lo[i] = (__bf16)(a - (float)hi[i]);
            x2loc = fmaf(a, a, x2loc);
        }
        __syncthreads();                           // barrier-1: prev MFMA reads done

        // ---- B: 16 fire-and-forget DMA instrs (1 KB each, linear) ----
        const __bf16* btile = Bpack + ct * 32768;
        #pragma unroll
        for (int j = 0; j < 16; ++j) {
            int Lw = wave * 16 + j;                // wave-uniform slot
            __builtin_amdgcn_global_load_lds(
                (const glob_bf16*)(btile + (size_t)(Lw * 64 + lane) * 8),
                (lds_bf16*)&Bs[Lw * 512], 16, 0, 0);
        }
        // ---- A stores (overlap B DMA latency) ----
        *(bf16x8*)&As[0][lane][wave * 8] = hi;
        *(bf16x8*)&As[1][lane][wave * 8] = lo;

        __syncthreads();                           // barrier-2: vmcnt(0) drains DMA

        // ---- prefetch A for ct+1 (plain global->VGPR; no barrier drain) ----
        if (ct < 7) {
            #pragma unroll
            for (int i = 0; i < 8; ++i)
                a_regs[i] = pqA[(size_t)((ct + 1) * 32 + wave * 8 + i) * N_];
        }

        // ---- MFMA: pass1 a1*b1 (keep b1 frags), pass2 a1*b2, pass3 a2*b1 ----
        const int lk = quad * 8;
        bf16x8 a1[4], a2[4], b1v[8];
        #pragma unroll
        for (int mt = 0; mt < 4; ++mt) a1[mt] = *(const bf16x8*)&As[0][mt * 16 + lm][lk];
        #pragma unroll
        for (int nt = 0; nt < 8; ++nt) {
            b1v[nt] = *(const bf16x8*)&Bs[((size_t)(0 * 4 + quad) * 512 + wave * 128 + nt * 16 + lm) * 8];
            #pragma unroll
            for (int mt = 0; mt < 4; ++mt)
                acc[mt][nt] = __builtin_amdgcn_mfma_f32_16x16x32_bf16(a1[mt], b1v[nt], acc[mt][nt], 0, 0, 0);
        }
        #pragma unroll
        for (int nt = 0; nt < 8; ++nt) {
            bf16x8 b2 = *(const bf16x8*)&Bs[((size_t)(1 * 4 + quad) * 512 + wave * 128 + nt * 16 + lm) * 8];
            #pragma unroll
            for (int mt = 0; mt < 4; ++mt)
                acc[mt][nt] = __builtin_amdgcn_mfma_f32_16x16x32_bf16(a1[mt], b2, acc[mt][nt], 0, 0, 0);
        }
        #pragma unroll
        for (int mt = 0; mt < 4; ++mt) a2[mt] = *(const bf16x8*)&As[1][mt * 16 + lm][lk];
        #pragma unroll
        for (int nt = 0; nt < 8; ++nt)
            #pragma unroll
            for (int mt = 0; mt < 4; ++mt)
                acc[mt][nt] = __builtin_amdgcn_mfma_f32_16x16x32_bf16(a2[mt], b1v[nt], acc[mt][nt], 0, 0, 0);
    }

    __syncthreads();          // drain K-loop LDS reads (As reused below)
    xs[wave][lane] = x2loc;

    // ---- epilogue: per-wave top-2 over its 128 codes -> LDS cross-wave merge ----
    P2* mergebuf = (P2*)&As[0][0][0];   // 4 KB, overlays dead As

    const int kbase = wave * 128;
    float e2v[8];
    #pragma unroll
    for (int nt = 0; nt < 8; ++nt) e2v[nt] = e2[kbase + nt * 16 + lm];

    #pragma unroll
    for (int mt = 0; mt < 4; ++mt) {
        #pragma unroll
        for (int r = 0; r < 4; ++r) {
            float v1 = __builtin_inff(), v2 = __builtin_inff();
            int k1 = 0x7fffffff, k2 = 0x7fffffff;
            #pragma unroll
            for (int nt = 0; nt < 8; ++nt) {
                float v = fmaf(-2.f, acc[mt][nt][r], e2v[nt]);
                ins2(v, kbase + nt * 16 + lm, v1, k1, v2, k2);
            }
            #pragma unroll
            for (int m = 1; m < 16; m <<= 1) {
                float ov1 = __shfl_xor(v1, m); int ok1 = __shfl_xor(k1, m);
                float ov2 = __shfl_xor(v2, m); int ok2 = __shfl_xor(k2, m);
                ins2(ov1, ok1, v1, k1, v2, k2);
                ins2(ov2, ok2, v1, k1, v2, k2);
            }
            if (lm == 0) {
                P2 p; p.v1 = v1; p.k1 = k1; p.v2 = v2; p.k2 = k2;
                mergebuf[wave * 64 + mt * 16 + quad * 4 + r] = p;
            }
        }
    }
    __syncthreads();          // mergebuf + xs visible

    if (tid < 64) {
        float v1 = __builtin_inff(), v2 = __builtin_inff();
        int k1 = 0x7fffffff, k2 = 0x7fffffff;
        #pragma unroll
        for (int w = 0; w < 4; ++w) {
            P2 p = mergebuf[w * 64 + tid];
            ins2(p.v1, p.k1, v1, k1, v2, k2);
            ins2(p.v2, p.k2, v1, k1, v2, k2);
        }
        P2 p; p.v1 = v1; p.k1 = k1; p.v2 = v2; p.k2 = k2;
        partials[Mtile * 64 + tid] = p;
        x2[Mtile * 64 + tid] = xs[0][tid] + xs[1][tid] + xs[2][tid] + xs[3][tid];
    }
}

// ---------------- kernel 3: fused refine + loss + gather ----------------------
// Output flat position p uses the winner of query row sigma(p) (H/W swap).
#define MARGIN 0.05f
__global__ void scatter_merge_kernel(const P2* __restrict__ partials,
                                     const float* __restrict__ x2arr,
                                     const float* __restrict__ pq,
                                     const float* __restrict__ cb,
                                     double* __restrict__ lossAcc,
                                     float* __restrict__ out) {
    int ntile = blockIdx.x, b = blockIdx.y, tid = threadIdx.x;
    int wave = tid >> 6;
    __shared__ int idxs[64];
    __shared__ double lred[4];
    __shared__ float tile[64][65];

    double myloss = 0.0;
    if (tid < 64) {
        int p = ntile * 64 + tid;                       // output flat spatial pos
        int s = ((p & 63) << 6) | (p >> 6);             // sigma (involution)
        int row = (b << 12) | s;
        P2 pp = partials[row];
        float v1 = pp.v1, v2 = pp.v2;
        int k1 = pp.k1, k2 = pp.k2;
        int kwin = k1;
        double d2min;
        if (v2 - v1 < MARGIN) {
            const float* xp  = pq + (size_t)b * (C_ * N_) + s;
            const float* ca  = cb + (size_t)k1 * C_;
            const float* cbp = cb + (size_t)k2 * C_;
            double da = 0.0, db = 0.0;
            for (int c = 0; c < C_; ++c) {
                double xv = (double)xp[(size_t)c * N_];
                double ea = xv - (double)ca[c];  da += ea * ea;
                double eb = xv - (double)cbp[c]; db += eb * eb;
            }
            if (db < da || (db == da && k2 < k1)) { kwin = k2; d2min = db; }
            else d2min = da;
        } else {
            d2min = (double)(x2arr[row] + v1);
        }
        idxs[tid] = kwin;
        myloss = d2min;
    }
    double sd = myloss;
    #pragma unroll
    for (int off = 32; off; off >>= 1) sd += __shfl_down(sd, off);
    if ((tid & 63) == 0) lred[wave] = sd;
    __syncthreads();
    if (tid == 0) atomicAdd(lossAcc, lred[0] + lred[1] + lred[2] + lred[3]);

    for (int cc = 0; cc < 4; ++cc) {
        int c0 = cc * 64;
        #pragma unroll
        for (int pp = 0; pp < 16; ++pp) {
            int i = pp * 4 + (tid >> 6);
            int c = tid & 63;
            tile[i][c] = cb[(size_t)idxs[i] * C_ + c0 + c];   // coalesced rows
        }
        __syncthreads();
        #pragma unroll
        for (int pp = 0; pp < 16; ++pp) {
            int cl = pp * 4 + (tid >> 6);
            int nl = tid & 63;
            out[((size_t)(b * C_ + c0 + cl)) * N_ + ntile * 64 + nl] = tile[nl][cl];
        }
        __syncthreads();
    }
}

// ---------------- kernel 4: loss finalize ------------------------------------
__global__ void finalize_kernel(const double* __restrict__ lossAcc, float* __restrict__ out) {
    out[(size_t)B_ * C_ * N_] =
        (float)(1.25 * (*lossAcc) / (double)((size_t)B_ * N_ * C_));
}

// ---------------- launch ------------------------------------------------------
extern "C" void kernel_launch(void* const* d_in, const int* in_sizes, int n_in,
                              void* d_out, int out_size, void* d_ws, size_t ws_size,
                              hipStream_t stream) {
    const float* pq = (const float*)d_in[0];   // [16,256,64,64]
    const float* cb = (const float*)d_in[1];   // [512,256]
    float* out = (float*)d_out;                // 4194304 out + 1 loss
    char* ws = (char*)d_ws;
    double* lossAcc = (double*)ws;                            // 16 B
    float*  e2    = (float*)(ws + 16);                        // 2 KB
    float*  x2    = (float*)(ws + 16 + 2048);                 // 256 KB
    __bf16* Bpack = (__bf16*)(ws + 16 + 2048 + 262144);       // 512 KB
    P2* partials  = (P2*)(ws + 16 + 2048 + 262144 + 524288);  // 1 MB

    prep_kernel<<<K_, 64, 0, stream>>>(cb, e2, Bpack, lossAcc);
    main_kernel<<<1024, 256, 0, stream>>>(pq, Bpack, e2, partials, x2);
    scatter_merge_kernel<<<dim3(HW_, B_), 256, 0, stream>>>(partials, x2, pq, cb, lossAcc, out);
    finalize_kernel<<<1, 1, 0, stream>>>(lossAcc, out);
}